// Round 4
// baseline (1223.783 us; speedup 1.0000x reference)
//
#include <hip/hip_runtime.h>
#include <hip/hip_bf16.h>

#define T_TOK 2048   // BATCH*SEQLEN
#define LSEQ  1024
#define DM    1024
#define DI    2048

using bf16 = __hip_bfloat16;
typedef __attribute__((ext_vector_type(8))) short short8;
typedef __attribute__((ext_vector_type(4))) float floatx4;

__device__ inline float to_f(float v) { return v; }
__device__ inline float to_f(bf16 v) { return __bfloat162float(v); }
__device__ inline bf16  f2bf(float v) { return __float2bfloat16(v); }

// load 8 contiguous elements as bf16 bit-pattern (converting if fp32 source)
__device__ inline short8 ld8(const bf16* p) { return *(const short8*)p; }
__device__ inline short8 ld8(const float* p) {
    short8 r;
#pragma unroll
    for (int i = 0; i < 8; ++i) {
        bf16 b = __float2bfloat16(p[i]);
        r[i] = __builtin_bit_cast(short, b);
    }
    return r;
}

// ---------------------------------------------------------------------------
// GEMM: C[M,N] = A[M,K] @ W[N,K]^T ; A/W fp32 or bf16 (K-contiguous),
// converted to bf16 during LDS staging. fp32 accum via 16x16x32 bf16 MFMA.
// 128x128 tile, BK=32, 4 waves (2x2 of 64x64).
// EPI: 0 = bf16 c
//      1 = fp32 c
//      2 = bf16 softplus(c + bias)
//      3 = fp32 c + residF
//      4 = bf16 relu(c + bias)
//      5 = fp32 clamp(c + bias + residF, +-1e4)  (final store; clamp = forensics)
// ---------------------------------------------------------------------------
template<typename TA, typename TW, int EPI>
__launch_bounds__(256, 2)
__global__ void gemm_bt(const TA* __restrict__ A, int lda,
                        const TW* __restrict__ W, int K,
                        float* __restrict__ outF, bf16* __restrict__ outB, int ldc,
                        const float* __restrict__ bias,
                        const float* __restrict__ residF)
{
    __shared__ __align__(16) bf16 sA[128 * 32];
    __shared__ __align__(16) bf16 sW[128 * 32];
    const int tid  = threadIdx.x;
    const int lane = tid & 63, wid = tid >> 6;
    const int m0 = blockIdx.x * 128, n0 = blockIdx.y * 128;
    const int wm = (wid >> 1) * 64, wn = (wid & 1) * 64;
    const int lr = lane & 15, lh = lane >> 4;
    // staging: thread handles elems [tid*8,+8) and [2048+tid*8,+8) of 128x32 tile
    const int i0 = tid * 8, i1 = 2048 + tid * 8;
    const int ar0 = i0 >> 5, ac0 = i0 & 31;   // rows 0..63
    const int ar1 = i1 >> 5, ac1 = i1 & 31;   // rows 64..127

    floatx4 acc[4][4];
#pragma unroll
    for (int i = 0; i < 4; ++i)
#pragma unroll
        for (int j = 0; j < 4; ++j) acc[i][j] = (floatx4){0.f, 0.f, 0.f, 0.f};

    const TA* Ab = A + (size_t)m0 * lda;
    const TW* Wb = W + (size_t)n0 * K;

    for (int k0 = 0; k0 < K; k0 += 32) {
        short8 a0 = ld8(Ab + (size_t)ar0 * lda + k0 + ac0);
        short8 a1 = ld8(Ab + (size_t)ar1 * lda + k0 + ac1);
        short8 w0 = ld8(Wb + (size_t)ar0 * K + k0 + ac0);
        short8 w1 = ld8(Wb + (size_t)ar1 * K + k0 + ac1);
        __syncthreads();   // previous iteration's LDS reads must finish
        *(short8*)(sA + i0) = a0;
        *(short8*)(sA + i1) = a1;
        *(short8*)(sW + i0) = w0;
        *(short8*)(sW + i1) = w1;
        __syncthreads();

        short8 af[4], wf[4];
#pragma unroll
        for (int i = 0; i < 4; ++i)
            af[i] = *(const short8*)(sA + (wm + i * 16 + lr) * 32 + lh * 8);
#pragma unroll
        for (int j = 0; j < 4; ++j)
            wf[j] = *(const short8*)(sW + (wn + j * 16 + lr) * 32 + lh * 8);
#pragma unroll
        for (int i = 0; i < 4; ++i)
#pragma unroll
            for (int j = 0; j < 4; ++j)
                acc[i][j] = __builtin_amdgcn_mfma_f32_16x16x32_bf16(af[i], wf[j], acc[i][j], 0, 0, 0);
    }

    // epilogue: C/D layout col=lane&15, row=(lane>>4)*4+reg  [m89/m91-verified]
#pragma unroll
    for (int i = 0; i < 4; ++i) {
#pragma unroll
        for (int j = 0; j < 4; ++j) {
#pragma unroll
            for (int r = 0; r < 4; ++r) {
                int row = m0 + wm + i * 16 + lh * 4 + r;
                int col = n0 + wn + j * 16 + lr;
                size_t off = (size_t)row * ldc + col;
                float c = acc[i][j][r];
                if (EPI == 0) {
                    outB[off] = f2bf(c);
                } else if (EPI == 1) {
                    outF[off] = c;
                } else if (EPI == 2) {
                    float v = c + bias[col];
                    outB[off] = f2bf((v > 15.f) ? v : log1pf(__expf(v)));
                } else if (EPI == 3) {
                    outF[off] = c + residF[off];
                } else if (EPI == 4) {
                    float v = c + bias[col];
                    outB[off] = f2bf(v > 0.f ? v : 0.f);
                } else if (EPI == 5) {
                    float v = c + bias[col] + residF[off];
                    v = fminf(fmaxf(v, -1e4f), 1e4f);   // forensic clamp (inert if correct)
                    outF[off] = v;
                }
            }
        }
    }
}

// ---------------------------------------------------------------------------
// LayerNorm over 1024 dims (fp32 in, fp32 params), one block per token, bf16 out
// ---------------------------------------------------------------------------
__launch_bounds__(256)
__global__ void ln_kernel(const float* __restrict__ x, const float* __restrict__ g,
                          const float* __restrict__ bb, bf16* __restrict__ out)
{
    int t = blockIdx.x, tid = threadIdx.x;
    const float* xr = x + (size_t)t * DM;
    float v[4], s = 0.f, ss = 0.f;
#pragma unroll
    for (int i = 0; i < 4; ++i) {
        v[i] = xr[tid + i * 256];
        s += v[i]; ss += v[i] * v[i];
    }
#pragma unroll
    for (int o = 1; o < 64; o <<= 1) { s += __shfl_xor(s, o); ss += __shfl_xor(ss, o); }
    __shared__ float red[8];
    int lane = tid & 63, wid = tid >> 6;
    if (lane == 0) { red[wid] = s; red[wid + 4] = ss; }
    __syncthreads();
    s  = red[0] + red[1] + red[2] + red[3];
    ss = red[4] + red[5] + red[6] + red[7];
    float mu  = s * (1.f / DM);
    float var = ss * (1.f / DM) - mu * mu;
    float rs  = rsqrtf(var + 1e-5f);
#pragma unroll
    for (int i = 0; i < 4; ++i) {
        int c = tid + i * 256;
        out[(size_t)t * DM + c] = f2bf((v[i] - mu) * rs * g[c] + bb[c]);
    }
}

// ---------------------------------------------------------------------------
// depthwise causal conv (k=4, fp32 weights) + bias + SiLU -> bf16
// ---------------------------------------------------------------------------
__launch_bounds__(256)
__global__ void conv_silu(const bf16* __restrict__ xz, const float* __restrict__ cw,
                          const float* __restrict__ cb, bf16* __restrict__ xcb)
{
    int idx = blockIdx.x * 256 + threadIdx.x;   // T_TOK*DI
    int d  = idx & (DI - 1);
    int tk = idx >> 11;
    int t  = tk & (LSEQ - 1);
    float acc = cb[d];
    float w0 = cw[d * 4 + 0], w1 = cw[d * 4 + 1];
    float w2 = cw[d * 4 + 2], w3 = cw[d * 4 + 3];
    if (t >= 3) acc += w0 * to_f(xz[(size_t)(tk - 3) * 4096 + d]);
    if (t >= 2) acc += w1 * to_f(xz[(size_t)(tk - 2) * 4096 + d]);
    if (t >= 1) acc += w2 * to_f(xz[(size_t)(tk - 1) * 4096 + d]);
    acc += w3 * to_f(xz[(size_t)tk * 4096 + d]);
    float s = acc / (1.f + __expf(-acc));
    xcb[idx] = f2bf(s);
}

// pad x_proj_w fp32 [96,2048] -> bf16 [128,2048] with zero rows
__launch_bounds__(256)
__global__ void padw_kernel(const float* __restrict__ w, bf16* __restrict__ wp)
{
    int idx = blockIdx.x * 256 + threadIdx.x;   // 128*2048
    int row = idx >> 11;
    wp[idx] = (row < 96) ? f2bf(w[idx]) : f2bf(0.f);
}

// ---------------------------------------------------------------------------
// selective scan: 16 lanes per (b,d) chain, one state per lane.
// h[n](t) = exp(dt*A[d,n])*h[n](t-1) + dt*B[t,n]*xc ; y = sum_n h*C[t,n]
// fused: y = (y + D*xc) * silu(z) -> bf16.  Y aliases xc (in-place): all 16
// lanes read xc[t] before lane0 stores y[t] (same wave, program order).
// ---------------------------------------------------------------------------
__launch_bounds__(256)
__global__ void scan_kernel(const bf16* __restrict__ dt, const bf16* xc,
                            const float* __restrict__ xdbl, const bf16* __restrict__ xz,
                            const float* __restrict__ A_log, const float* __restrict__ Dp,
                            bf16* Y)
{
    int tid = blockIdx.x * 256 + threadIdx.x;
    int n = tid & 15;
    int g = tid >> 4;           // chain id: b*2048 + d
    int d = g & (DI - 1);
    int b = g >> 11;
    float a  = -__expf(A_log[d * 16 + n]);
    float Dd = Dp[d];
    float h = 0.f;
    const bf16*  dt_p = dt   + (size_t)b * LSEQ * DI + d;
    const bf16*  xc_p = xc   + (size_t)b * LSEQ * DI + d;
    const float* xd_p = xdbl + (size_t)b * LSEQ * 128;
    const bf16*  z_p  = xz   + (size_t)b * LSEQ * 4096 + DI + d;
    bf16* y_p = Y + (size_t)b * LSEQ * DI + d;
    for (int t = 0; t < LSEQ; ++t) {
        float dtv = to_f(dt_p[(size_t)t * DI]);
        float xv  = to_f(xc_p[(size_t)t * DI]);
        float Bv  = xd_p[t * 128 + 64 + n];
        float Cv  = xd_p[t * 128 + 80 + n];
        float dA  = __expf(dtv * a);
        h = fmaf(dA, h, dtv * Bv * xv);
        float p = h * Cv;
        p += __shfl_xor(p, 1);
        p += __shfl_xor(p, 2);
        p += __shfl_xor(p, 4);
        p += __shfl_xor(p, 8);
        if (n == 0) {
            float zv = to_f(z_p[(size_t)t * 4096]);
            float yv = (p + Dd * xv) * (zv / (1.f + __expf(-zv)));
            y_p[(size_t)t * DI] = f2bf(yv);
        }
    }
}

// ---------------------------------------------------------------------------
extern "C" void kernel_launch(void* const* d_in, const int* in_sizes, int n_in,
                              void* d_out, int out_size, void* d_ws, size_t ws_size,
                              hipStream_t stream)
{
    // ALL inputs are fp32 (reference uses jnp.float32 throughout)
    const float* x       = (const float*)d_in[0];
    const float* in_proj = (const float*)d_in[1];
    const float* conv_w  = (const float*)d_in[2];
    const float* conv_b  = (const float*)d_in[3];
    const float* x_proj  = (const float*)d_in[4];
    const float* dt_w    = (const float*)d_in[5];
    const float* dt_b    = (const float*)d_in[6];
    const float* A_log   = (const float*)d_in[7];
    const float* Dp      = (const float*)d_in[8];
    const float* out_w   = (const float*)d_in[9];
    const float* ln1g    = (const float*)d_in[10];
    const float* ln1b    = (const float*)d_in[11];
    const float* ln2g    = (const float*)d_in[12];
    const float* ln2b    = (const float*)d_in[13];
    const float* fw1     = (const float*)d_in[14];
    const float* fb1     = (const float*)d_in[15];
    const float* fw2     = (const float*)d_in[16];
    const float* fb2     = (const float*)d_in[17];
    float* out = (float*)d_out;   // fp32 output

    // workspace layout: 45.5 MB total (lifetime-aliased)
    char* w = (char*)d_ws;
    bf16*  h1   = (bf16*)(w);                 // 4MB  @0   LN1/LN2 out
    bf16*  xz   = (bf16*)(w + (4u  << 20));   // 16MB @4   in_proj out; later f1
    bf16*  xc   = (bf16*)(w + (20u << 20));   // 8MB  @20  conv out; scan Y in-place
    float* xdf  = (float*)(w + (28u << 20));  // 1MB  @28  x_dbl fp32
    bf16*  dtb  = (bf16*)(w + (29u << 20));   // 8MB  @29  dt
    float* x2   = (float*)(w + (37u << 20));  // 8MB  @37  post-mamba residual fp32
    bf16*  Wpad = (bf16*)(w + (45u << 20));   // 0.5MB @45 padded x_proj_w (bf16)
    bf16*  Yb = xc;                           // in-place
    bf16*  f1 = xz;                           // reuse after scan

    // 1. LN1 (fp32 in -> bf16 out)
    ln_kernel<<<dim3(T_TOK), dim3(256), 0, stream>>>(x, ln1g, ln1b, h1);
    // 2. in_proj: xz = h1 @ in_proj^T  [2048,4096] bf16
    gemm_bt<bf16, float, 0><<<dim3(16, 32), dim3(256), 0, stream>>>(
        h1, DM, in_proj, DM, nullptr, xz, 4096, nullptr, nullptr);
    // 3. causal depthwise conv + SiLU -> xc
    conv_silu<<<dim3(T_TOK * DI / 256), dim3(256), 0, stream>>>(xz, conv_w, conv_b, xc);
    // 4. pad + cvt x_proj_w -> Wpad bf16 [128,2048]
    padw_kernel<<<dim3(128 * 2048 / 256), dim3(256), 0, stream>>>(x_proj, Wpad);
    // 5. x_proj: x_dbl = xc @ Wpad^T  [2048,128] fp32
    gemm_bt<bf16, bf16, 1><<<dim3(16, 1), dim3(256), 0, stream>>>(
        xc, DI, Wpad, DI, xdf, nullptr, 128, nullptr, nullptr);
    // 6. dt = softplus(x_dbl[:, :64] @ dt_w^T + dt_b)  [2048,2048] bf16
    gemm_bt<float, float, 2><<<dim3(16, 16), dim3(256), 0, stream>>>(
        xdf, 128, dt_w, 64, nullptr, dtb, DI, dt_b, nullptr);
    // 7. selective scan + D*xc + z-gate -> Y (in-place over xc)
    scan_kernel<<<dim3(256), dim3(256), 0, stream>>>(dtb, xc, xdf, xz, A_log, Dp, Yb);
    // 8. out_proj + residual: x2 = x + Y @ out_w^T  fp32
    gemm_bt<bf16, float, 3><<<dim3(16, 8), dim3(256), 0, stream>>>(
        Yb, DI, out_w, DI, x2, nullptr, DM, nullptr, x);
    // 9. LN2
    ln_kernel<<<dim3(T_TOK), dim3(256), 0, stream>>>(x2, ln2g, ln2b, h1);
    // 10. FFN1: f1 = relu(h1 @ fw1^T + fb1) bf16
    gemm_bt<bf16, float, 4><<<dim3(16, 32), dim3(256), 0, stream>>>(
        h1, DM, fw1, DM, nullptr, f1, 4096, fb1, nullptr);
    // 11. FFN2 + bias + residual -> out fp32
    gemm_bt<bf16, float, 5><<<dim3(16, 8), dim3(256), 0, stream>>>(
        f1, 4096, fw2, 4096, out, nullptr, DM, fb2, x2);
}

// Round 5
// 721.579 us; speedup vs baseline: 1.6960x; 1.6960x over previous
//
#include <hip/hip_runtime.h>
#include <hip/hip_bf16.h>

#define T_TOK 2048   // BATCH*SEQLEN
#define LSEQ  1024
#define DM    1024
#define DI    2048

using bf16 = __hip_bfloat16;
typedef __attribute__((ext_vector_type(8))) short short8;
typedef __attribute__((ext_vector_type(4))) float floatx4;

__device__ inline float to_f(float v) { return v; }
__device__ inline float to_f(bf16 v) { return __bfloat162float(v); }
__device__ inline bf16  f2bf(float v) { return __float2bfloat16(v); }

// load 8 contiguous elements as bf16 bit-pattern (converting if fp32 source)
__device__ inline short8 ld8(const bf16* p) { return *(const short8*)p; }
__device__ inline short8 ld8(const float* p) {
    floatx4 f0 = *(const floatx4*)p;        // 16B vector load
    floatx4 f1 = *(const floatx4*)(p + 4);  // 16B vector load
    short8 r;
#pragma unroll
    for (int i = 0; i < 4; ++i) {
        r[i]     = __builtin_bit_cast(short, __float2bfloat16(f0[i]));
        r[i + 4] = __builtin_bit_cast(short, __float2bfloat16(f1[i]));
    }
    return r;
}

// ---------------------------------------------------------------------------
// GEMM: C[M,N] = A[M,K] @ W[N,K]^T ; A/W fp32 or bf16 (K-contiguous),
// converted to bf16 during LDS staging. fp32 accum via 16x16x32 bf16 MFMA.
// 128x128 tile, BK=32, 4 waves (2x2 of 64x64).
// EPI: 0 = bf16 c          1 = fp32 c
//      2 = bf16 softplus(c + bias)
//      3 = fp32 c + residF
//      4 = bf16 relu(c + bias)
//      5 = fp32 c + bias + residF
// ---------------------------------------------------------------------------
template<typename TA, typename TW, int EPI>
__launch_bounds__(256, 2)
__global__ void gemm_bt(const TA* __restrict__ A, int lda,
                        const TW* __restrict__ W, int K,
                        float* __restrict__ outF, bf16* __restrict__ outB, int ldc,
                        const float* __restrict__ bias,
                        const float* __restrict__ residF)
{
    __shared__ __align__(16) bf16 sA[128 * 32];
    __shared__ __align__(16) bf16 sW[128 * 32];
    const int tid  = threadIdx.x;
    const int lane = tid & 63, wid = tid >> 6;
    const int m0 = blockIdx.x * 128, n0 = blockIdx.y * 128;
    const int wm = (wid >> 1) * 64, wn = (wid & 1) * 64;
    const int lr = lane & 15, lh = lane >> 4;
    // staging: thread handles elems [tid*8,+8) and [2048+tid*8,+8) of 128x32 tile
    const int i0 = tid * 8, i1 = 2048 + tid * 8;
    const int ar0 = i0 >> 5, ac0 = i0 & 31;   // rows 0..63
    const int ar1 = i1 >> 5, ac1 = i1 & 31;   // rows 64..127

    floatx4 acc[4][4];
#pragma unroll
    for (int i = 0; i < 4; ++i)
#pragma unroll
        for (int j = 0; j < 4; ++j) acc[i][j] = (floatx4){0.f, 0.f, 0.f, 0.f};

    const TA* Ab = A + (size_t)m0 * lda;
    const TW* Wb = W + (size_t)n0 * K;

    for (int k0 = 0; k0 < K; k0 += 32) {
        short8 a0 = ld8(Ab + (size_t)ar0 * lda + k0 + ac0);
        short8 a1 = ld8(Ab + (size_t)ar1 * lda + k0 + ac1);
        short8 w0 = ld8(Wb + (size_t)ar0 * K + k0 + ac0);
        short8 w1 = ld8(Wb + (size_t)ar1 * K + k0 + ac1);
        __syncthreads();   // previous iteration's LDS reads must finish
        *(short8*)(sA + i0) = a0;
        *(short8*)(sA + i1) = a1;
        *(short8*)(sW + i0) = w0;
        *(short8*)(sW + i1) = w1;
        __syncthreads();

        short8 af[4], wf[4];
#pragma unroll
        for (int i = 0; i < 4; ++i)
            af[i] = *(const short8*)(sA + (wm + i * 16 + lr) * 32 + lh * 8);
#pragma unroll
        for (int j = 0; j < 4; ++j)
            wf[j] = *(const short8*)(sW + (wn + j * 16 + lr) * 32 + lh * 8);
#pragma unroll
        for (int i = 0; i < 4; ++i)
#pragma unroll
            for (int j = 0; j < 4; ++j)
                acc[i][j] = __builtin_amdgcn_mfma_f32_16x16x32_bf16(af[i], wf[j], acc[i][j], 0, 0, 0);
    }

    // epilogue: C/D layout col=lane&15, row=(lane>>4)*4+reg  [m89/m91-verified]
#pragma unroll
    for (int i = 0; i < 4; ++i) {
#pragma unroll
        for (int j = 0; j < 4; ++j) {
#pragma unroll
            for (int r = 0; r < 4; ++r) {
                int row = m0 + wm + i * 16 + lh * 4 + r;
                int col = n0 + wn + j * 16 + lr;
                size_t off = (size_t)row * ldc + col;
                float c = acc[i][j][r];
                if (EPI == 0) {
                    outB[off] = f2bf(c);
                } else if (EPI == 1) {
                    outF[off] = c;
                } else if (EPI == 2) {
                    float v = c + bias[col];
                    outB[off] = f2bf((v > 15.f) ? v : log1pf(__expf(v)));
                } else if (EPI == 3) {
                    outF[off] = c + residF[off];
                } else if (EPI == 4) {
                    float v = c + bias[col];
                    outB[off] = f2bf(v > 0.f ? v : 0.f);
                } else if (EPI == 5) {
                    outF[off] = c + bias[col] + residF[off];
                }
            }
        }
    }
}

// ---------------------------------------------------------------------------
// LayerNorm over 1024 dims (fp32 in/params), one block per token, bf16 out
// ---------------------------------------------------------------------------
__launch_bounds__(256)
__global__ void ln_kernel(const float* __restrict__ x, const float* __restrict__ g,
                          const float* __restrict__ bb, bf16* __restrict__ out)
{
    int t = blockIdx.x, tid = threadIdx.x;
    const float* xr = x + (size_t)t * DM;
    float v[4], s = 0.f, ss = 0.f;
#pragma unroll
    for (int i = 0; i < 4; ++i) {
        v[i] = xr[tid + i * 256];
        s += v[i]; ss += v[i] * v[i];
    }
#pragma unroll
    for (int o = 1; o < 64; o <<= 1) { s += __shfl_xor(s, o); ss += __shfl_xor(ss, o); }
    __shared__ float red[8];
    int lane = tid & 63, wid = tid >> 6;
    if (lane == 0) { red[wid] = s; red[wid + 4] = ss; }
    __syncthreads();
    s  = red[0] + red[1] + red[2] + red[3];
    ss = red[4] + red[5] + red[6] + red[7];
    float mu  = s * (1.f / DM);
    float var = ss * (1.f / DM) - mu * mu;
    float rs  = rsqrtf(var + 1e-5f);
#pragma unroll
    for (int i = 0; i < 4; ++i) {
        int c = tid + i * 256;
        out[(size_t)t * DM + c] = f2bf((v[i] - mu) * rs * g[c] + bb[c]);
    }
}

// ---------------------------------------------------------------------------
// depthwise causal conv (k=4, fp32 weights) + bias + SiLU -> bf16
// ---------------------------------------------------------------------------
__launch_bounds__(256)
__global__ void conv_silu(const bf16* __restrict__ xz, const float* __restrict__ cw,
                          const float* __restrict__ cb, bf16* __restrict__ xcb)
{
    int idx = blockIdx.x * 256 + threadIdx.x;   // T_TOK*DI
    int d  = idx & (DI - 1);
    int tk = idx >> 11;
    int t  = tk & (LSEQ - 1);
    float acc = cb[d];
    float w0 = cw[d * 4 + 0], w1 = cw[d * 4 + 1];
    float w2 = cw[d * 4 + 2], w3 = cw[d * 4 + 3];
    if (t >= 3) acc += w0 * to_f(xz[(size_t)(tk - 3) * 4096 + d]);
    if (t >= 2) acc += w1 * to_f(xz[(size_t)(tk - 2) * 4096 + d]);
    if (t >= 1) acc += w2 * to_f(xz[(size_t)(tk - 1) * 4096 + d]);
    acc += w3 * to_f(xz[(size_t)tk * 4096 + d]);
    float s = acc / (1.f + __expf(-acc));
    xcb[idx] = f2bf(s);
}

// pad x_proj_w fp32 [96,2048] -> bf16 [128,2048] with zero rows
__launch_bounds__(256)
__global__ void padw_kernel(const float* __restrict__ w, bf16* __restrict__ wp)
{
    int idx = blockIdx.x * 256 + threadIdx.x;   // 128*2048
    int row = idx >> 11;
    wp[idx] = (row < 96) ? f2bf(w[idx]) : f2bf(0.f);
}

// ---------------------------------------------------------------------------
// selective scan: 16 lanes per (b,d) chain, one state per lane.
// Double-buffered 8-step register batches hide load latency; the only serial
// chain is h = fma(dA, h, dBx).
// ---------------------------------------------------------------------------
struct Batch8 { float dtv[8], xv[8], Bv[8], Cv[8], zv[8]; };

__device__ __forceinline__ void load8(int t0, int n,
        const bf16* dt_p, const bf16* xc_p, const float* xd_p, const bf16* z_p,
        Batch8& b)
{
#pragma unroll
    for (int u = 0; u < 8; ++u) {
        int t = t0 + u;
        b.dtv[u] = to_f(dt_p[(size_t)t * DI]);
        b.xv[u]  = to_f(xc_p[(size_t)t * DI]);
        b.Bv[u]  = xd_p[t * 128 + 64 + n];
        b.Cv[u]  = xd_p[t * 128 + 80 + n];
        b.zv[u]  = to_f(z_p[(size_t)t * 4096]);
    }
}

__device__ __forceinline__ void comp8(int t0, int n, float a, float Dd, float& h,
                                      bf16* y_p, const Batch8& b)
{
#pragma unroll
    for (int u = 0; u < 8; ++u) {
        float dA = __expf(b.dtv[u] * a);
        h = fmaf(dA, h, b.dtv[u] * b.Bv[u] * b.xv[u]);
        float p = h * b.Cv[u];
        p += __shfl_xor(p, 1);
        p += __shfl_xor(p, 2);
        p += __shfl_xor(p, 4);
        p += __shfl_xor(p, 8);
        if (n == 0) {
            float zv = b.zv[u];
            float yv = (p + Dd * b.xv[u]) * (zv / (1.f + __expf(-zv)));
            y_p[(size_t)(t0 + u) * DI] = f2bf(yv);
        }
    }
}

__launch_bounds__(256)
__global__ void scan_kernel(const bf16* __restrict__ dt, const bf16* xc,
                            const float* __restrict__ xdbl, const bf16* __restrict__ xz,
                            const float* __restrict__ A_log, const float* __restrict__ Dp,
                            bf16* Y)
{
    int tid = blockIdx.x * 256 + threadIdx.x;
    int n = tid & 15;
    int g = tid >> 4;           // chain id: b*2048 + d
    int d = g & (DI - 1);
    int b = g >> 11;
    float a  = -__expf(A_log[d * 16 + n]);
    float Dd = Dp[d];
    float h = 0.f;
    const bf16*  dt_p = dt   + (size_t)b * LSEQ * DI + d;
    const bf16*  xc_p = xc   + (size_t)b * LSEQ * DI + d;
    const float* xd_p = xdbl + (size_t)b * LSEQ * 128;
    const bf16*  z_p  = xz   + (size_t)b * LSEQ * 4096 + DI + d;
    bf16* y_p = Y + (size_t)b * LSEQ * DI + d;

    Batch8 bufA, bufB;
    load8(0, n, dt_p, xc_p, xd_p, z_p, bufA);
    for (int t0 = 0; t0 < LSEQ; t0 += 16) {
        load8(t0 + 8, n, dt_p, xc_p, xd_p, z_p, bufB);
        comp8(t0, n, a, Dd, h, y_p, bufA);
        load8((t0 + 16 < LSEQ) ? t0 + 16 : 0, n, dt_p, xc_p, xd_p, z_p, bufA);
        comp8(t0 + 8, n, a, Dd, h, y_p, bufB);
    }
}

// ---------------------------------------------------------------------------
extern "C" void kernel_launch(void* const* d_in, const int* in_sizes, int n_in,
                              void* d_out, int out_size, void* d_ws, size_t ws_size,
                              hipStream_t stream)
{
    // ALL inputs fp32 (reference uses jnp.float32 throughout); output fp32
    const float* x       = (const float*)d_in[0];
    const float* in_proj = (const float*)d_in[1];
    const float* conv_w  = (const float*)d_in[2];
    const float* conv_b  = (const float*)d_in[3];
    const float* x_proj  = (const float*)d_in[4];
    const float* dt_w    = (const float*)d_in[5];
    const float* dt_b    = (const float*)d_in[6];
    const float* A_log   = (const float*)d_in[7];
    const float* Dp      = (const float*)d_in[8];
    const float* out_w   = (const float*)d_in[9];
    const float* ln1g    = (const float*)d_in[10];
    const float* ln1b    = (const float*)d_in[11];
    const float* ln2g    = (const float*)d_in[12];
    const float* ln2b    = (const float*)d_in[13];
    const float* fw1     = (const float*)d_in[14];
    const float* fb1     = (const float*)d_in[15];
    const float* fw2     = (const float*)d_in[16];
    const float* fb2     = (const float*)d_in[17];
    float* out = (float*)d_out;

    // workspace layout: 45.5 MB total (lifetime-aliased)
    char* w = (char*)d_ws;
    bf16*  h1   = (bf16*)(w);                 // 4MB  @0   LN1/LN2 out
    bf16*  xz   = (bf16*)(w + (4u  << 20));   // 16MB @4   in_proj out; later f1
    bf16*  xc   = (bf16*)(w + (20u << 20));   // 8MB  @20  conv out; scan Y in-place
    float* xdf  = (float*)(w + (28u << 20));  // 1MB  @28  x_dbl fp32
    bf16*  dtb  = (bf16*)(w + (29u << 20));   // 8MB  @29  dt
    float* x2   = (float*)(w + (37u << 20));  // 8MB  @37  post-mamba residual fp32
    bf16*  Wpad = (bf16*)(w + (45u << 20));   // 0.5MB @45 padded x_proj_w (bf16)
    bf16*  Yb = xc;                           // in-place
    bf16*  f1 = xz;                           // reuse after scan

    // 1. LN1 (fp32 in -> bf16 out)
    ln_kernel<<<dim3(T_TOK), dim3(256), 0, stream>>>(x, ln1g, ln1b, h1);
    // 2. in_proj: xz = h1 @ in_proj^T  [2048,4096] bf16
    gemm_bt<bf16, float, 0><<<dim3(16, 32), dim3(256), 0, stream>>>(
        h1, DM, in_proj, DM, nullptr, xz, 4096, nullptr, nullptr);
    // 3. causal depthwise conv + SiLU -> xc
    conv_silu<<<dim3(T_TOK * DI / 256), dim3(256), 0, stream>>>(xz, conv_w, conv_b, xc);
    // 4. pad + cvt x_proj_w -> Wpad bf16 [128,2048]
    padw_kernel<<<dim3(128 * 2048 / 256), dim3(256), 0, stream>>>(x_proj, Wpad);
    // 5. x_proj: x_dbl = xc @ Wpad^T  [2048,128] fp32
    gemm_bt<bf16, bf16, 1><<<dim3(16, 1), dim3(256), 0, stream>>>(
        xc, DI, Wpad, DI, xdf, nullptr, 128, nullptr, nullptr);
    // 6. dt = softplus(x_dbl[:, :64] @ dt_w^T + dt_b)  [2048,2048] bf16
    gemm_bt<float, float, 2><<<dim3(16, 16), dim3(256), 0, stream>>>(
        xdf, 128, dt_w, 64, nullptr, dtb, DI, dt_b, nullptr);
    // 7. selective scan + D*xc + z-gate -> Y (in-place over xc)
    scan_kernel<<<dim3(256), dim3(256), 0, stream>>>(dtb, xc, xdf, xz, A_log, Dp, Yb);
    // 8. out_proj + residual: x2 = x + Y @ out_w^T  fp32
    gemm_bt<bf16, float, 3><<<dim3(16, 8), dim3(256), 0, stream>>>(
        Yb, DI, out_w, DI, x2, nullptr, DM, nullptr, x);
    // 9. LN2
    ln_kernel<<<dim3(T_TOK), dim3(256), 0, stream>>>(x2, ln2g, ln2b, h1);
    // 10. FFN1: f1 = relu(h1 @ fw1^T + fb1) bf16
    gemm_bt<bf16, float, 4><<<dim3(16, 32), dim3(256), 0, stream>>>(
        h1, DM, fw1, DM, nullptr, f1, 4096, fb1, nullptr);
    // 11. FFN2 + bias + residual -> out fp32
    gemm_bt<bf16, float, 5><<<dim3(16, 8), dim3(256), 0, stream>>>(
        f1, 4096, fw2, 4096, out, nullptr, DM, fb2, x2);
}

// Round 7
// 647.384 us; speedup vs baseline: 1.8904x; 1.1146x over previous
//
#include <hip/hip_runtime.h>
#include <hip/hip_bf16.h>

#define T_TOK 2048   // BATCH*SEQLEN
#define LSEQ  1024
#define DM    1024
#define DI    2048
#define NCH   8      // scan chunks
#define CLEN  128    // LSEQ/NCH

using bf16 = __hip_bfloat16;
typedef __attribute__((ext_vector_type(8))) short short8;
typedef __attribute__((ext_vector_type(4))) float floatx4;

__device__ inline float to_f(float v) { return v; }
__device__ inline float to_f(bf16 v) { return __bfloat162float(v); }
__device__ inline bf16  f2bf(float v) { return __float2bfloat16(v); }

// load 8 contiguous elements as bf16 bit-pattern (converting if fp32 source)
__device__ inline short8 ld8(const bf16* p) { return *(const short8*)p; }
__device__ inline short8 ld8(const float* p) {
    floatx4 f0 = *(const floatx4*)p;
    floatx4 f1 = *(const floatx4*)(p + 4);
    short8 r;
#pragma unroll
    for (int i = 0; i < 4; ++i) {
        r[i]     = __builtin_bit_cast(short, __float2bfloat16(f0[i]));
        r[i + 4] = __builtin_bit_cast(short, __float2bfloat16(f1[i]));
    }
    return r;
}

// ---------------------------------------------------------------------------
// GEMM: C[M,N] = A[M,K] @ W[N,K]^T ; A/W fp32 or bf16 (K-contiguous),
// converted to bf16 during LDS staging. fp32 accum via 16x16x32 bf16 MFMA.
// 128x128 tile, BK=32, 4 waves (2x2 of 64x64).
// EPI: 0 = bf16 c          1 = fp32 c
//      2 = bf16 softplus(c + bias)
//      3 = fp32 c + residF
//      4 = bf16 relu(c + bias)
//      5 = fp32 c + bias + residF
// ---------------------------------------------------------------------------
template<typename TA, typename TW, int EPI>
__launch_bounds__(256, 2)
__global__ void gemm_bt(const TA* __restrict__ A, int lda,
                        const TW* __restrict__ W, int K,
                        float* __restrict__ outF, bf16* __restrict__ outB, int ldc,
                        const float* __restrict__ bias,
                        const float* __restrict__ residF)
{
    __shared__ __align__(16) bf16 sA[128 * 32];
    __shared__ __align__(16) bf16 sW[128 * 32];
    const int tid  = threadIdx.x;
    const int lane = tid & 63, wid = tid >> 6;
    const int m0 = blockIdx.x * 128, n0 = blockIdx.y * 128;
    const int wm = (wid >> 1) * 64, wn = (wid & 1) * 64;
    const int lr = lane & 15, lh = lane >> 4;
    const int i0 = tid * 8, i1 = 2048 + tid * 8;
    const int ar0 = i0 >> 5, ac0 = i0 & 31;
    const int ar1 = i1 >> 5, ac1 = i1 & 31;

    floatx4 acc[4][4];
#pragma unroll
    for (int i = 0; i < 4; ++i)
#pragma unroll
        for (int j = 0; j < 4; ++j) acc[i][j] = (floatx4){0.f, 0.f, 0.f, 0.f};

    const TA* Ab = A + (size_t)m0 * lda;
    const TW* Wb = W + (size_t)n0 * K;

    for (int k0 = 0; k0 < K; k0 += 32) {
        short8 a0 = ld8(Ab + (size_t)ar0 * lda + k0 + ac0);
        short8 a1 = ld8(Ab + (size_t)ar1 * lda + k0 + ac1);
        short8 w0 = ld8(Wb + (size_t)ar0 * K + k0 + ac0);
        short8 w1 = ld8(Wb + (size_t)ar1 * K + k0 + ac1);
        __syncthreads();
        *(short8*)(sA + i0) = a0;
        *(short8*)(sA + i1) = a1;
        *(short8*)(sW + i0) = w0;
        *(short8*)(sW + i1) = w1;
        __syncthreads();

        short8 af[4], wf[4];
#pragma unroll
        for (int i = 0; i < 4; ++i)
            af[i] = *(const short8*)(sA + (wm + i * 16 + lr) * 32 + lh * 8);
#pragma unroll
        for (int j = 0; j < 4; ++j)
            wf[j] = *(const short8*)(sW + (wn + j * 16 + lr) * 32 + lh * 8);
#pragma unroll
        for (int i = 0; i < 4; ++i)
#pragma unroll
            for (int j = 0; j < 4; ++j)
                acc[i][j] = __builtin_amdgcn_mfma_f32_16x16x32_bf16(af[i], wf[j], acc[i][j], 0, 0, 0);
    }

#pragma unroll
    for (int i = 0; i < 4; ++i) {
#pragma unroll
        for (int j = 0; j < 4; ++j) {
#pragma unroll
            for (int r = 0; r < 4; ++r) {
                int row = m0 + wm + i * 16 + lh * 4 + r;
                int col = n0 + wn + j * 16 + lr;
                size_t off = (size_t)row * ldc + col;
                float c = acc[i][j][r];
                if (EPI == 0) {
                    outB[off] = f2bf(c);
                } else if (EPI == 1) {
                    outF[off] = c;
                } else if (EPI == 2) {
                    float v = c + bias[col];
                    outB[off] = f2bf((v > 15.f) ? v : log1pf(__expf(v)));
                } else if (EPI == 3) {
                    outF[off] = c + residF[off];
                } else if (EPI == 4) {
                    float v = c + bias[col];
                    outB[off] = f2bf(v > 0.f ? v : 0.f);
                } else if (EPI == 5) {
                    outF[off] = c + bias[col] + residF[off];
                }
            }
        }
    }
}

// ---------------------------------------------------------------------------
// LayerNorm over 1024 dims (fp32 in/params), one block per token, bf16 out
// ---------------------------------------------------------------------------
__launch_bounds__(256)
__global__ void ln_kernel(const float* __restrict__ x, const float* __restrict__ g,
                          const float* __restrict__ bb, bf16* __restrict__ out)
{
    int t = blockIdx.x, tid = threadIdx.x;
    const float* xr = x + (size_t)t * DM;
    float v[4], s = 0.f, ss = 0.f;
#pragma unroll
    for (int i = 0; i < 4; ++i) {
        v[i] = xr[tid + i * 256];
        s += v[i]; ss += v[i] * v[i];
    }
#pragma unroll
    for (int o = 1; o < 64; o <<= 1) { s += __shfl_xor(s, o); ss += __shfl_xor(ss, o); }
    __shared__ float red[8];
    int lane = tid & 63, wid = tid >> 6;
    if (lane == 0) { red[wid] = s; red[wid + 4] = ss; }
    __syncthreads();
    s  = red[0] + red[1] + red[2] + red[3];
    ss = red[4] + red[5] + red[6] + red[7];
    float mu  = s * (1.f / DM);
    float var = ss * (1.f / DM) - mu * mu;
    float rs  = rsqrtf(var + 1e-5f);
#pragma unroll
    for (int i = 0; i < 4; ++i) {
        int c = tid + i * 256;
        out[(size_t)t * DM + c] = f2bf((v[i] - mu) * rs * g[c] + bb[c]);
    }
}

// ---------------------------------------------------------------------------
// depthwise causal conv (k=4, fp32 weights) + bias + SiLU -> bf16
// ---------------------------------------------------------------------------
__launch_bounds__(256)
__global__ void conv_silu(const bf16* __restrict__ xz, const float* __restrict__ cw,
                          const float* __restrict__ cb, bf16* __restrict__ xcb)
{
    int idx = blockIdx.x * 256 + threadIdx.x;   // T_TOK*DI
    int d  = idx & (DI - 1);
    int tk = idx >> 11;
    int t  = tk & (LSEQ - 1);
    float acc = cb[d];
    float w0 = cw[d * 4 + 0], w1 = cw[d * 4 + 1];
    float w2 = cw[d * 4 + 2], w3 = cw[d * 4 + 3];
    if (t >= 3) acc += w0 * to_f(xz[(size_t)(tk - 3) * 4096 + d]);
    if (t >= 2) acc += w1 * to_f(xz[(size_t)(tk - 2) * 4096 + d]);
    if (t >= 1) acc += w2 * to_f(xz[(size_t)(tk - 1) * 4096 + d]);
    acc += w3 * to_f(xz[(size_t)tk * 4096 + d]);
    float s = acc / (1.f + __expf(-acc));
    xcb[idx] = f2bf(s);
}

// pad x_proj_w fp32 [96,2048] -> bf16 [128,2048] with zero rows
__launch_bounds__(256)
__global__ void padw_kernel(const float* __restrict__ w, bf16* __restrict__ wp)
{
    int idx = blockIdx.x * 256 + threadIdx.x;   // 128*2048
    int row = idx >> 11;
    wp[idx] = (row < 96) ? f2bf(w[idx]) : f2bf(0.f);
}

// ---------------------------------------------------------------------------
// Chunked selective scan (2 phases). Chain = (b,d), 16 lanes (one state each).
// L split into NCH chunks of CLEN -> 8192 waves = 8/SIMD.
// Phase 1 (scan_local): local scan per chunk with h_in=0 -> p_local(t) bf16,
//   per-lane chunk decay P = exp(a*sum dt) and local h_end.
// Phase 2 (scan_fixup): inline prefix over Pbuf/hend (<=7 fma) gives h_in;
//   p(t) = p_local(t) + sum_n exp(a_n*S(t)) * h_in_n * C_n(t);
//   y = (p + D*xc) * silu(z)  (in-place over xc).
// ---------------------------------------------------------------------------
__launch_bounds__(256)
__global__ void scan_local(const bf16* __restrict__ dt, const bf16* __restrict__ xc,
                           const float* __restrict__ xdbl, const float* __restrict__ A_log,
                           bf16* __restrict__ p_loc, float* __restrict__ Pbuf,
                           float* __restrict__ hend)
{
    int T  = blockIdx.x * 256 + threadIdx.x;   // 524288
    int n  = T & 15;
    int g2 = T >> 4;
    int d  = g2 & (DI - 1);
    int c  = (g2 >> 11) & (NCH - 1);
    int b  = g2 >> 14;
    float a = -__expf(A_log[d * 16 + n]);
    const bf16*  dt_p = dt   + (size_t)b * LSEQ * DI + d;
    const bf16*  xc_p = xc   + (size_t)b * LSEQ * DI + d;
    const float* xd_p = xdbl + (size_t)b * LSEQ * 128;
    bf16* p_p = p_loc + (size_t)b * LSEQ * DI + d;
    const int t0 = c * CLEN;
    float h = 0.f, S = 0.f;
    for (int tb = t0; tb < t0 + CLEN; tb += 8) {
        float dtv[8], xv[8], Bv[8], Cv[8];
#pragma unroll
        for (int u = 0; u < 8; ++u) {
            int t = tb + u;
            dtv[u] = to_f(dt_p[(size_t)t * DI]);
            xv[u]  = to_f(xc_p[(size_t)t * DI]);
            Bv[u]  = xd_p[t * 128 + 64 + n];
            Cv[u]  = xd_p[t * 128 + 80 + n];
        }
#pragma unroll
        for (int u = 0; u < 8; ++u) {
            float dA = __expf(dtv[u] * a);
            h = fmaf(dA, h, dtv[u] * Bv[u] * xv[u]);
            S += dtv[u];
            float p = h * Cv[u];
            p += __shfl_xor(p, 1);
            p += __shfl_xor(p, 2);
            p += __shfl_xor(p, 4);
            p += __shfl_xor(p, 8);
            if (n == 0) p_p[(size_t)(tb + u) * DI] = f2bf(p);
        }
    }
    int idx = ((b * NCH + c) * DI + d) * 16 + n;
    Pbuf[idx] = __expf(a * S);
    hend[idx] = h;
}

__launch_bounds__(256)
__global__ void scan_fixup(const bf16* __restrict__ dt, const bf16* xc,
                           const float* __restrict__ xdbl, const bf16* __restrict__ xz,
                           const bf16* __restrict__ p_loc,
                           const float* __restrict__ Pbuf, const float* __restrict__ hend,
                           const float* __restrict__ A_log, const float* __restrict__ Dp,
                           bf16* Y)
{
    int T  = blockIdx.x * 256 + threadIdx.x;
    int n  = T & 15;
    int g2 = T >> 4;
    int d  = g2 & (DI - 1);
    int c  = (g2 >> 11) & (NCH - 1);
    int b  = g2 >> 14;
    float a  = -__expf(A_log[d * 16 + n]);
    float Dd = Dp[d];
    // inline chunk-prefix: h_in for chunk c from per-chunk (P, h_end) pairs
    float hc = 0.f;
    for (int cc = 0; cc < c; ++cc) {
        int idx = ((b * NCH + cc) * DI + d) * 16 + n;
        hc = fmaf(Pbuf[idx], hc, hend[idx]);
    }
    const bf16*  dt_p = dt    + (size_t)b * LSEQ * DI + d;
    const bf16*  xc_p = xc    + (size_t)b * LSEQ * DI + d;
    const float* xd_p = xdbl  + (size_t)b * LSEQ * 128;
    const bf16*  z_p  = xz    + (size_t)b * LSEQ * 4096 + DI + d;
    const bf16*  pl_p = p_loc + (size_t)b * LSEQ * DI + d;
    bf16* y_p = Y + (size_t)b * LSEQ * DI + d;
    const int t0 = c * CLEN;
    float S = 0.f;
    for (int tb = t0; tb < t0 + CLEN; tb += 8) {
        float dtv[8], xv[8], Cv[8], zv[8], pl[8];
#pragma unroll
        for (int u = 0; u < 8; ++u) {
            int t = tb + u;
            dtv[u] = to_f(dt_p[(size_t)t * DI]);
            xv[u]  = to_f(xc_p[(size_t)t * DI]);
            Cv[u]  = xd_p[t * 128 + 80 + n];
            zv[u]  = to_f(z_p[(size_t)t * 4096]);
            pl[u]  = to_f(pl_p[(size_t)t * DI]);
        }
#pragma unroll
        for (int u = 0; u < 8; ++u) {
            S += dtv[u];
            float q = __expf(a * S) * hc * Cv[u];
            q += __shfl_xor(q, 1);
            q += __shfl_xor(q, 2);
            q += __shfl_xor(q, 4);
            q += __shfl_xor(q, 8);
            if (n == 0) {
                float p  = pl[u] + q;
                float yv = (p + Dd * xv[u]) * (zv[u] / (1.f + __expf(-zv[u])));
                y_p[(size_t)(tb + u) * DI] = f2bf(yv);
            }
        }
    }
}

// ---------------------------------------------------------------------------
extern "C" void kernel_launch(void* const* d_in, const int* in_sizes, int n_in,
                              void* d_out, int out_size, void* d_ws, size_t ws_size,
                              hipStream_t stream)
{
    // ALL inputs fp32; output fp32
    const float* x       = (const float*)d_in[0];
    const float* in_proj = (const float*)d_in[1];
    const float* conv_w  = (const float*)d_in[2];
    const float* conv_b  = (const float*)d_in[3];
    const float* x_proj  = (const float*)d_in[4];
    const float* dt_w    = (const float*)d_in[5];
    const float* dt_b    = (const float*)d_in[6];
    const float* A_log   = (const float*)d_in[7];
    const float* Dp      = (const float*)d_in[8];
    const float* out_w   = (const float*)d_in[9];
    const float* ln1g    = (const float*)d_in[10];
    const float* ln1b    = (const float*)d_in[11];
    const float* ln2g    = (const float*)d_in[12];
    const float* ln2b    = (const float*)d_in[13];
    const float* fw1     = (const float*)d_in[14];
    const float* fb1     = (const float*)d_in[15];
    const float* fw2     = (const float*)d_in[16];
    const float* fb2     = (const float*)d_in[17];
    float* out = (float*)d_out;

    // workspace layout: 45.5 MB total (lifetime-aliased)
    //  @0  4MB   h1 (LN out)        | scan: Pbuf @0..2, hend @2..4
    //  @4  16MB  xz (in_proj out)   | after scan: f1
    //  @20 8MB   xc (conv out)      | scan writes Y in-place
    //  @28 1MB   xdf (x_dbl fp32)
    //  @29 8MB   dtb (dt bf16)
    //  @37 8MB   p_loc (bf16, FULL 8MB)  | after fixup: x2 (fp32)
    //  @45 0.5MB Wpad
    char* w = (char*)d_ws;
    bf16*  h1   = (bf16*)(w);
    bf16*  xz   = (bf16*)(w + (4u  << 20));
    bf16*  xc   = (bf16*)(w + (20u << 20));
    float* xdf  = (float*)(w + (28u << 20));
    bf16*  dtb  = (bf16*)(w + (29u << 20));
    bf16*  p_loc= (bf16*)(w + (37u << 20));
    float* x2   = (float*)(w + (37u << 20));
    bf16*  Wpad = (bf16*)(w + (45u << 20));
    float* Pbuf = (float*)(w);
    float* hend = (float*)(w + (2u << 20));
    bf16*  Yb = xc;
    bf16*  f1 = xz;

    // 1. LN1 (fp32 in -> bf16 out)
    ln_kernel<<<dim3(T_TOK), dim3(256), 0, stream>>>(x, ln1g, ln1b, h1);
    // 2. in_proj: xz = h1 @ in_proj^T  [2048,4096] bf16
    gemm_bt<bf16, float, 0><<<dim3(16, 32), dim3(256), 0, stream>>>(
        h1, DM, in_proj, DM, nullptr, xz, 4096, nullptr, nullptr);
    // 3. causal depthwise conv + SiLU -> xc
    conv_silu<<<dim3(T_TOK * DI / 256), dim3(256), 0, stream>>>(xz, conv_w, conv_b, xc);
    // 4. pad + cvt x_proj_w -> Wpad bf16 [128,2048]
    padw_kernel<<<dim3(128 * 2048 / 256), dim3(256), 0, stream>>>(x_proj, Wpad);
    // 5. x_proj: x_dbl = xc @ Wpad^T  [2048,128] fp32
    gemm_bt<bf16, bf16, 1><<<dim3(16, 1), dim3(256), 0, stream>>>(
        xc, DI, Wpad, DI, xdf, nullptr, 128, nullptr, nullptr);
    // 6. dt = softplus(x_dbl[:, :64] @ dt_w^T + dt_b)  [2048,2048] bf16
    gemm_bt<float, float, 2><<<dim3(16, 16), dim3(256), 0, stream>>>(
        xdf, 128, dt_w, 64, nullptr, dtb, DI, dt_b, nullptr);
    // 7. chunked selective scan (2 phases) + gate -> Y (in-place over xc)
    scan_local<<<dim3(2048), dim3(256), 0, stream>>>(dtb, xc, xdf, A_log, p_loc, Pbuf, hend);
    scan_fixup<<<dim3(2048), dim3(256), 0, stream>>>(dtb, xc, xdf, xz, p_loc, Pbuf, hend,
                                                     A_log, Dp, Yb);
    // 8. out_proj + residual: x2 = x + Y @ out_w^T  fp32 (x2 overwrites p_loc - dead)
    gemm_bt<bf16, float, 3><<<dim3(16, 8), dim3(256), 0, stream>>>(
        Yb, DI, out_w, DI, x2, nullptr, DM, nullptr, x);
    // 9. LN2 (overwrites Pbuf/hend - dead)
    ln_kernel<<<dim3(T_TOK), dim3(256), 0, stream>>>(x2, ln2g, ln2b, h1);
    // 10. FFN1: f1 = relu(h1 @ fw1^T + fb1) bf16
    gemm_bt<bf16, float, 4><<<dim3(16, 32), dim3(256), 0, stream>>>(
        h1, DM, fw1, DM, nullptr, f1, 4096, fb1, nullptr);
    // 11. FFN2 + bias + residual -> out fp32
    gemm_bt<bf16, float, 5><<<dim3(16, 8), dim3(256), 0, stream>>>(
        f1, 4096, fw2, 4096, out, nullptr, DM, fb2, x2);
}

// Round 8
// 603.130 us; speedup vs baseline: 2.0291x; 1.0734x over previous
//
#include <hip/hip_runtime.h>
#include <hip/hip_bf16.h>

#define T_TOK 2048   // BATCH*SEQLEN
#define LSEQ  1024
#define DM    1024
#define DI    2048
#define NCH   8      // scan chunks
#define CLEN  128    // LSEQ/NCH
#define LDW   40     // padded LDS row stride (bf16 elems): 8-way->2-way bank conflicts

using bf16 = __hip_bfloat16;
typedef __attribute__((ext_vector_type(8))) short short8;
typedef __attribute__((ext_vector_type(4))) float floatx4;

__device__ inline float to_f(float v) { return v; }
__device__ inline float to_f(bf16 v) { return __bfloat162float(v); }
__device__ inline bf16  f2bf(float v) { return __float2bfloat16(v); }

// load 8 contiguous elements as bf16 bit-pattern (converting if fp32 source)
__device__ inline short8 ld8(const bf16* p) { return *(const short8*)p; }
__device__ inline short8 ld8(const float* p) {
    floatx4 f0 = *(const floatx4*)p;
    floatx4 f1 = *(const floatx4*)(p + 4);
    short8 r;
#pragma unroll
    for (int i = 0; i < 4; ++i) {
        r[i]     = __builtin_bit_cast(short, __float2bfloat16(f0[i]));
        r[i + 4] = __builtin_bit_cast(short, __float2bfloat16(f1[i]));
    }
    return r;
}

// ---------------------------------------------------------------------------
// GEMM: C[M,N] = A[M,K] @ W[N,K]^T ; 128x128 tile, BK=32, 4 waves (2x2 of
// 64x64), 16x16x32 bf16 MFMA, fp32 accum. Register-prefetch pipelined K-loop:
// loads for iter k+1 issue before iter k's MFMAs -> latency hidden.
// KS>1: split-K, blockIdx.z picks a K-slice, epilogue must be EPI 6.
// EPI: 0 = bf16 c
//      2 = bf16 softplus(c + bias)
//      4 = bf16 relu(c + bias)
//      6 = atomicAdd fp32 c   (bias/resid handled by pre-fill pass)
// ---------------------------------------------------------------------------
template<typename TA, typename TW, int EPI, int KS>
__launch_bounds__(256, 2)
__global__ void gemm_bt(const TA* __restrict__ A, int lda,
                        const TW* __restrict__ W, int K,
                        float* __restrict__ outF, bf16* __restrict__ outB, int ldc,
                        const float* __restrict__ bias)
{
    __shared__ __align__(16) bf16 sA[128 * LDW];
    __shared__ __align__(16) bf16 sW[128 * LDW];
    const int tid  = threadIdx.x;
    const int lane = tid & 63, wid = tid >> 6;
    const int m0 = blockIdx.x * 128, n0 = blockIdx.y * 128;
    const int wm = (wid >> 1) * 64, wn = (wid & 1) * 64;
    const int lr = lane & 15, lh = lane >> 4;
    // staging: thread handles rows ar0 (0..63) and ar1 (64..127), 8 cols each
    const int ar0 = tid >> 2, ac = (tid & 3) * 8;
    const int ar1 = ar0 + 64;
    const int s0 = ar0 * LDW + ac, s1 = ar1 * LDW + ac;

    const int kBeg = blockIdx.z * (K / KS);
    const int kEnd = kBeg + K / KS;

    floatx4 acc[4][4];
#pragma unroll
    for (int i = 0; i < 4; ++i)
#pragma unroll
        for (int j = 0; j < 4; ++j) acc[i][j] = (floatx4){0.f, 0.f, 0.f, 0.f};

    const TA* Ab = A + (size_t)m0 * lda;
    const TW* Wb = W + (size_t)n0 * K;

    // prologue: prefetch first tile into registers
    short8 a0 = ld8(Ab + (size_t)ar0 * lda + kBeg + ac);
    short8 a1 = ld8(Ab + (size_t)ar1 * lda + kBeg + ac);
    short8 w0 = ld8(Wb + (size_t)ar0 * K + kBeg + ac);
    short8 w1 = ld8(Wb + (size_t)ar1 * K + kBeg + ac);

    for (int k0 = kBeg; k0 < kEnd; k0 += 32) {
        __syncthreads();   // prev iteration's LDS reads complete
        *(short8*)(sA + s0) = a0;   // waits vmcnt for the prefetched loads
        *(short8*)(sA + s1) = a1;
        *(short8*)(sW + s0) = w0;
        *(short8*)(sW + s1) = w1;
        __syncthreads();

        // prefetch next tile (issued BEFORE the MFMAs -> latency overlapped)
        int kn = (k0 + 32 < kEnd) ? k0 + 32 : kBeg;
        a0 = ld8(Ab + (size_t)ar0 * lda + kn + ac);
        a1 = ld8(Ab + (size_t)ar1 * lda + kn + ac);
        w0 = ld8(Wb + (size_t)ar0 * K + kn + ac);
        w1 = ld8(Wb + (size_t)ar1 * K + kn + ac);

        short8 af[4], wf[4];
#pragma unroll
        for (int i = 0; i < 4; ++i)
            af[i] = *(const short8*)(sA + (wm + i * 16 + lr) * LDW + lh * 8);
#pragma unroll
        for (int j = 0; j < 4; ++j)
            wf[j] = *(const short8*)(sW + (wn + j * 16 + lr) * LDW + lh * 8);
#pragma unroll
        for (int i = 0; i < 4; ++i)
#pragma unroll
            for (int j = 0; j < 4; ++j)
                acc[i][j] = __builtin_amdgcn_mfma_f32_16x16x32_bf16(af[i], wf[j], acc[i][j], 0, 0, 0);
    }

    // epilogue: C/D layout col=lane&15, row=(lane>>4)*4+reg  [m89/m91-verified]
#pragma unroll
    for (int i = 0; i < 4; ++i) {
#pragma unroll
        for (int j = 0; j < 4; ++j) {
#pragma unroll
            for (int r = 0; r < 4; ++r) {
                int row = m0 + wm + i * 16 + lh * 4 + r;
                int col = n0 + wn + j * 16 + lr;
                size_t off = (size_t)row * ldc + col;
                float c = acc[i][j][r];
                if (EPI == 0) {
                    outB[off] = f2bf(c);
                } else if (EPI == 2) {
                    float v = c + bias[col];
                    outB[off] = f2bf((v > 15.f) ? v : log1pf(__expf(v)));
                } else if (EPI == 4) {
                    float v = c + bias[col];
                    outB[off] = f2bf(v > 0.f ? v : 0.f);
                } else if (EPI == 6) {
                    atomicAdd(outF + off, c);
                }
            }
        }
    }
}

// ---------------------------------------------------------------------------
// LayerNorm over 1024 dims (fp32 in/params), one block per token, bf16 out
// ---------------------------------------------------------------------------
__launch_bounds__(256)
__global__ void ln_kernel(const float* __restrict__ x, const float* __restrict__ g,
                          const float* __restrict__ bb, bf16* __restrict__ out)
{
    int t = blockIdx.x, tid = threadIdx.x;
    const float* xr = x + (size_t)t * DM;
    float v[4], s = 0.f, ss = 0.f;
#pragma unroll
    for (int i = 0; i < 4; ++i) {
        v[i] = xr[tid + i * 256];
        s += v[i]; ss += v[i] * v[i];
    }
#pragma unroll
    for (int o = 1; o < 64; o <<= 1) { s += __shfl_xor(s, o); ss += __shfl_xor(ss, o); }
    __shared__ float red[8];
    int lane = tid & 63, wid = tid >> 6;
    if (lane == 0) { red[wid] = s; red[wid + 4] = ss; }
    __syncthreads();
    s  = red[0] + red[1] + red[2] + red[3];
    ss = red[4] + red[5] + red[6] + red[7];
    float mu  = s * (1.f / DM);
    float var = ss * (1.f / DM) - mu * mu;
    float rs  = rsqrtf(var + 1e-5f);
#pragma unroll
    for (int i = 0; i < 4; ++i) {
        int c = tid + i * 256;
        out[(size_t)t * DM + c] = f2bf((v[i] - mu) * rs * g[c] + bb[c]);
    }
}

// ---------------------------------------------------------------------------
// depthwise causal conv (k=4, fp32 weights) + bias + SiLU -> bf16
// ---------------------------------------------------------------------------
__launch_bounds__(256)
__global__ void conv_silu(const bf16* __restrict__ xz, const float* __restrict__ cw,
                          const float* __restrict__ cb, bf16* __restrict__ xcb)
{
    int idx = blockIdx.x * 256 + threadIdx.x;   // T_TOK*DI
    int d  = idx & (DI - 1);
    int tk = idx >> 11;
    int t  = tk & (LSEQ - 1);
    float acc = cb[d];
    float w0 = cw[d * 4 + 0], w1 = cw[d * 4 + 1];
    float w2 = cw[d * 4 + 2], w3 = cw[d * 4 + 3];
    if (t >= 3) acc += w0 * to_f(xz[(size_t)(tk - 3) * 4096 + d]);
    if (t >= 2) acc += w1 * to_f(xz[(size_t)(tk - 2) * 4096 + d]);
    if (t >= 1) acc += w2 * to_f(xz[(size_t)(tk - 1) * 4096 + d]);
    acc += w3 * to_f(xz[(size_t)tk * 4096 + d]);
    float s = acc / (1.f + __expf(-acc));
    xcb[idx] = f2bf(s);
}

// pad x_proj_w fp32 [96,2048] -> bf16 [128,2048] with zero rows
__launch_bounds__(256)
__global__ void padw_kernel(const float* __restrict__ w, bf16* __restrict__ wp)
{
    int idx = blockIdx.x * 256 + threadIdx.x;   // 128*2048
    int row = idx >> 11;
    wp[idx] = (row < 96) ? f2bf(w[idx]) : f2bf(0.f);
}

// pre-fill for FFN2 split-K: out[t,c] = fb2[c] + x2[t,c]
__launch_bounds__(256)
__global__ void fill_bias_resid(const float* __restrict__ bias, const float* __restrict__ resid,
                                float* __restrict__ out)
{
    int idx = blockIdx.x * 256 + threadIdx.x;   // T_TOK*DM
    out[idx] = bias[idx & (DM - 1)] + resid[idx];
}

// ---------------------------------------------------------------------------
// Chunked selective scan (2 phases). Chain = (b,d), 16 lanes (one state each).
// ---------------------------------------------------------------------------
__launch_bounds__(256)
__global__ void scan_local(const bf16* __restrict__ dt, const bf16* __restrict__ xc,
                           const float* __restrict__ xdbl, const float* __restrict__ A_log,
                           bf16* __restrict__ p_loc, float* __restrict__ Pbuf,
                           float* __restrict__ hend)
{
    int T  = blockIdx.x * 256 + threadIdx.x;   // 524288
    int n  = T & 15;
    int g2 = T >> 4;
    int d  = g2 & (DI - 1);
    int c  = (g2 >> 11) & (NCH - 1);
    int b  = g2 >> 14;
    float a = -__expf(A_log[d * 16 + n]);
    const bf16*  dt_p = dt   + (size_t)b * LSEQ * DI + d;
    const bf16*  xc_p = xc   + (size_t)b * LSEQ * DI + d;
    const float* xd_p = xdbl + (size_t)b * LSEQ * 128;
    bf16* p_p = p_loc + (size_t)b * LSEQ * DI + d;
    const int t0 = c * CLEN;
    float h = 0.f, S = 0.f;
    for (int tb = t0; tb < t0 + CLEN; tb += 8) {
        float dtv[8], xv[8], Bv[8], Cv[8];
#pragma unroll
        for (int u = 0; u < 8; ++u) {
            int t = tb + u;
            dtv[u] = to_f(dt_p[(size_t)t * DI]);
            xv[u]  = to_f(xc_p[(size_t)t * DI]);
            Bv[u]  = xd_p[t * 128 + 64 + n];
            Cv[u]  = xd_p[t * 128 + 80 + n];
        }
#pragma unroll
        for (int u = 0; u < 8; ++u) {
            float dA = __expf(dtv[u] * a);
            h = fmaf(dA, h, dtv[u] * Bv[u] * xv[u]);
            S += dtv[u];
            float p = h * Cv[u];
            p += __shfl_xor(p, 1);
            p += __shfl_xor(p, 2);
            p += __shfl_xor(p, 4);
            p += __shfl_xor(p, 8);
            if (n == 0) p_p[(size_t)(tb + u) * DI] = f2bf(p);
        }
    }
    int idx = ((b * NCH + c) * DI + d) * 16 + n;
    Pbuf[idx] = __expf(a * S);
    hend[idx] = h;
}

__launch_bounds__(256)
__global__ void scan_fixup(const bf16* __restrict__ dt, const bf16* xc,
                           const float* __restrict__ xdbl, const bf16* __restrict__ xz,
                           const bf16* __restrict__ p_loc,
                           const float* __restrict__ Pbuf, const float* __restrict__ hend,
                           const float* __restrict__ A_log, const float* __restrict__ Dp,
                           bf16* Y)
{
    int T  = blockIdx.x * 256 + threadIdx.x;
    int n  = T & 15;
    int g2 = T >> 4;
    int d  = g2 & (DI - 1);
    int c  = (g2 >> 11) & (NCH - 1);
    int b  = g2 >> 14;
    float a  = -__expf(A_log[d * 16 + n]);
    float Dd = Dp[d];
    float hc = 0.f;   // inline chunk-prefix (<=7 fma)
    for (int cc = 0; cc < c; ++cc) {
        int idx = ((b * NCH + cc) * DI + d) * 16 + n;
        hc = fmaf(Pbuf[idx], hc, hend[idx]);
    }
    const bf16*  dt_p = dt    + (size_t)b * LSEQ * DI + d;
    const bf16*  xc_p = xc    + (size_t)b * LSEQ * DI + d;
    const float* xd_p = xdbl  + (size_t)b * LSEQ * 128;
    const bf16*  z_p  = xz    + (size_t)b * LSEQ * 4096 + DI + d;
    const bf16*  pl_p = p_loc + (size_t)b * LSEQ * DI + d;
    bf16* y_p = Y + (size_t)b * LSEQ * DI + d;
    const int t0 = c * CLEN;
    float S = 0.f;
    for (int tb = t0; tb < t0 + CLEN; tb += 8) {
        float dtv[8], xv[8], Cv[8], zv[8], pl[8];
#pragma unroll
        for (int u = 0; u < 8; ++u) {
            int t = tb + u;
            dtv[u] = to_f(dt_p[(size_t)t * DI]);
            xv[u]  = to_f(xc_p[(size_t)t * DI]);
            Cv[u]  = xd_p[t * 128 + 80 + n];
            zv[u]  = to_f(z_p[(size_t)t * 4096]);
            pl[u]  = to_f(pl_p[(size_t)t * DI]);
        }
#pragma unroll
        for (int u = 0; u < 8; ++u) {
            S += dtv[u];
            float q = __expf(a * S) * hc * Cv[u];
            q += __shfl_xor(q, 1);
            q += __shfl_xor(q, 2);
            q += __shfl_xor(q, 4);
            q += __shfl_xor(q, 8);
            if (n == 0) {
                float p  = pl[u] + q;
                float yv = (p + Dd * xv[u]) * (zv[u] / (1.f + __expf(-zv[u])));
                y_p[(size_t)(tb + u) * DI] = f2bf(yv);
            }
        }
    }
}

// ---------------------------------------------------------------------------
extern "C" void kernel_launch(void* const* d_in, const int* in_sizes, int n_in,
                              void* d_out, int out_size, void* d_ws, size_t ws_size,
                              hipStream_t stream)
{
    // ALL inputs fp32; output fp32
    const float* x       = (const float*)d_in[0];
    const float* in_proj = (const float*)d_in[1];
    const float* conv_w  = (const float*)d_in[2];
    const float* conv_b  = (const float*)d_in[3];
    const float* x_proj  = (const float*)d_in[4];
    const float* dt_w    = (const float*)d_in[5];
    const float* dt_b    = (const float*)d_in[6];
    const float* A_log   = (const float*)d_in[7];
    const float* Dp      = (const float*)d_in[8];
    const float* out_w   = (const float*)d_in[9];
    const float* ln1g    = (const float*)d_in[10];
    const float* ln1b    = (const float*)d_in[11];
    const float* ln2g    = (const float*)d_in[12];
    const float* ln2b    = (const float*)d_in[13];
    const float* fw1     = (const float*)d_in[14];
    const float* fb1     = (const float*)d_in[15];
    const float* fw2     = (const float*)d_in[16];
    const float* fb2     = (const float*)d_in[17];
    float* out = (float*)d_out;

    // workspace layout: 45.5 MB total (lifetime-aliased)
    //  @0  4MB   h1 (LN out)        | scan: Pbuf @0..2, hend @2..4
    //  @4  16MB  xz (in_proj out)   | after scan: f1
    //  @20 8MB   xc (conv out)      | scan writes Y in-place
    //  @28 1MB   xdf (x_dbl fp32)
    //  @29 8MB   dtb (dt bf16)
    //  @37 8MB   p_loc (bf16)       | after fixup: x2 (fp32)
    //  @45 0.5MB Wpad
    char* w = (char*)d_ws;
    bf16*  h1   = (bf16*)(w);
    bf16*  xz   = (bf16*)(w + (4u  << 20));
    bf16*  xc   = (bf16*)(w + (20u << 20));
    float* xdf  = (float*)(w + (28u << 20));
    bf16*  dtb  = (bf16*)(w + (29u << 20));
    bf16*  p_loc= (bf16*)(w + (37u << 20));
    float* x2   = (float*)(w + (37u << 20));
    bf16*  Wpad = (bf16*)(w + (45u << 20));
    float* Pbuf = (float*)(w);
    float* hend = (float*)(w + (2u << 20));
    bf16*  Yb = xc;
    bf16*  f1 = xz;

    // 1. LN1 (fp32 in -> bf16 out)
    ln_kernel<<<dim3(T_TOK), dim3(256), 0, stream>>>(x, ln1g, ln1b, h1);
    // 2. in_proj: xz = h1 @ in_proj^T  [2048,4096] bf16
    gemm_bt<bf16, float, 0, 1><<<dim3(16, 32), dim3(256), 0, stream>>>(
        h1, DM, in_proj, DM, nullptr, xz, 4096, nullptr);
    // 3. causal depthwise conv + SiLU -> xc
    conv_silu<<<dim3(T_TOK * DI / 256), dim3(256), 0, stream>>>(xz, conv_w, conv_b, xc);
    // 4. pad + cvt x_proj_w -> Wpad bf16 [128,2048]
    padw_kernel<<<dim3(128 * 2048 / 256), dim3(256), 0, stream>>>(x_proj, Wpad);
    // 5. x_proj: x_dbl = xc @ Wpad^T  [2048,128] fp32, split-K x8 (zero-init + atomic)
    hipMemsetAsync(xdf, 0, (size_t)T_TOK * 128 * 4, stream);
    gemm_bt<bf16, bf16, 6, 8><<<dim3(16, 1, 8), dim3(256), 0, stream>>>(
        xc, DI, Wpad, DI, xdf, nullptr, 128, nullptr);
    // 6. dt = softplus(x_dbl[:, :64] @ dt_w^T + dt_b)  [2048,2048] bf16
    gemm_bt<float, float, 2, 1><<<dim3(16, 16), dim3(256), 0, stream>>>(
        xdf, 128, dt_w, 64, nullptr, dtb, DI, dt_b);
    // 7. chunked selective scan (2 phases) + gate -> Y (in-place over xc)
    scan_local<<<dim3(2048), dim3(256), 0, stream>>>(dtb, xc, xdf, A_log, p_loc, Pbuf, hend);
    scan_fixup<<<dim3(2048), dim3(256), 0, stream>>>(dtb, xc, xdf, xz, p_loc, Pbuf, hend,
                                                     A_log, Dp, Yb);
    // 8. out_proj + residual: x2 = x + Y @ out_w^T, split-K x4 (x2 pre-filled with x)
    hipMemcpyAsync(x2, x, (size_t)T_TOK * DM * 4, hipMemcpyDeviceToDevice, stream);
    gemm_bt<bf16, float, 6, 4><<<dim3(16, 8, 4), dim3(256), 0, stream>>>(
        Yb, DI, out_w, DI, x2, nullptr, DM, nullptr);
    // 9. LN2 (overwrites Pbuf/hend - dead)
    ln_kernel<<<dim3(T_TOK), dim3(256), 0, stream>>>(x2, ln2g, ln2b, h1);
    // 10. FFN1: f1 = relu(h1 @ fw1^T + fb1) bf16
    gemm_bt<bf16, float, 4, 1><<<dim3(16, 32), dim3(256), 0, stream>>>(
        h1, DM, fw1, DM, nullptr, f1, 4096, fb1);
    // 11. FFN2 + bias + residual -> out fp32, split-K x4 (out pre-filled fb2 + x2)
    fill_bias_resid<<<dim3(T_TOK * DM / 256), dim3(256), 0, stream>>>(fb2, x2, out);
    gemm_bt<bf16, float, 6, 4><<<dim3(16, 8, 4), dim3(256), 0, stream>>>(
        f1, 4096, fw2, 4096, out, nullptr, DM, nullptr);
}